// Round 1
// baseline (932.784 us; speedup 1.0000x reference)
//
#include <hip/hip_runtime.h>

#define BATCH 32
#define CIN_  64
#define COUT_ 64
#define H_    224
#define W_    224
#define HW_   (H_*W_)

#define HT     2            // output rows per block
#define WTILE  112          // output cols per block
#define XS_P   116          // padded pixels per LDS row (need 114)
#define NROWS  (HT+2)
#define NG     7            // N-groups of 32 outputs (2 rows x 16 px)

typedef __bf16 bf16x4 __attribute__((ext_vector_type(4)));
typedef __bf16 bf16x8 __attribute__((ext_vector_type(8)));
typedef float  f32x4  __attribute__((ext_vector_type(4)));
typedef float  f32x16 __attribute__((ext_vector_type(16)));

// Binarize weights: wp[tap][co][ci] = bf16(sign(w[co][ci][tap]))
__global__ void bc_prep(const float* __restrict__ w, __bf16* __restrict__ wp) {
    int gid = blockIdx.x * 256 + threadIdx.x;
    if (gid >= COUT_ * CIN_ * 9) return;
    int co  = gid / (CIN_ * 9);
    int rem = gid - co * (CIN_ * 9);
    int ci  = rem / 9;
    int t   = rem - ci * 9;
    float v = w[gid];
    float s = (v > 0.0f) ? 1.0f : ((v < 0.0f) ? -1.0f : 0.0f);
    wp[t * (COUT_ * CIN_) + co * CIN_ + ci] = (__bf16)s;
}

// Implicit-GEMM binary conv, 32x32x16 MFMA.
// Block: (b, h-tile of 2, w-tile of 112). 4 waves = (co-tile of 32) x (group parity).
// N=32 packs as 2 output rows x 16 cols. 36 A-frags (weights, 144 VGPR) live in regs.
// LDS x-tile: xs[row][px][ci] bf16, ci-chunk XOR-swizzled (swizzle is g-invariant).
__global__ __launch_bounds__(256, 2)
void bc_main(const float* __restrict__ x, const __bf16* __restrict__ wp,
             const float* __restrict__ bias, float* __restrict__ out) {
    __shared__ __attribute__((aligned(16))) __bf16 xs[NROWS * XS_P * 64];

    const int htile = blockIdx.x;     // 0..111
    const int wt    = blockIdx.y;     // 0..1
    const int bb    = blockIdx.z;     // 0..31
    const int h0 = htile * HT;
    const int w0 = wt * WTILE;

    const int tid  = threadIdx.x;
    const int lane = tid & 63;
    const int wave = tid >> 6;
    const int ct   = wave & 1;        // co-tile index (32 co each)
    const int gs   = wave >> 1;       // group parity
    const int col  = lane & 31;       // MFMA n / m index
    const int kh   = lane >> 5;       // k half (ci +0 / +8)

    // ---- A fragments: A[m=col][k=kh*8+j], k-step s: tap=s>>2, ci=(s&3)*16 ----
    bf16x8 afrag[36];
    {
        const int m = ct * 32 + col;
        #pragma unroll
        for (int s = 0; s < 36; ++s) {
            const int tap = s >> 2;
            const int cib = (s & 3) * 16 + kh * 8;
            afrag[s] = *(const bf16x8*)(wp + tap * (COUT_ * CIN_) + m * CIN_ + cib);
        }
    }
    // C/D row = (r&3) + 8*(r>>2) + 4*kh (+ ct*32)
    float biasr[16];
    #pragma unroll
    for (int r = 0; r < 16; ++r)
        biasr[r] = bias[ct * 32 + 4 * kh + (r & 3) + 8 * (r >> 2)];

    // ---- stage input tile: transpose NCHW -> xs[row][px][ci] (bf16) ----
    // xs px p corresponds to input w = w0 - 1 + p.
    const int cig   = tid >> 4;        // 0..15 : 4-ci group (4 per wave)
    const int ci0   = cig * 4;
    const int cc    = cig >> 1;        // 8-ci chunk index 0..7
    const int chalf = (cig & 1) * 4;   // offset inside chunk

    #pragma unroll
    for (int r = 0; r < NROWS; ++r) {
        const int hin = h0 - 1 + r;
        const bool rowok = (hin >= 0) && (hin < H_);
        const float* src = x + (size_t)bb * CIN_ * HW_ + (size_t)hin * W_;
        #pragma unroll
        for (int s = 0; s < 2; ++s) {
            const int pxg = (tid & 15) + s * 16;   // 0..31
            const int wbase = w0 - 4 + pxg * 4;    // aligned global w of elem 0
            float vv[4][4];
            #pragma unroll
            for (int j = 0; j < 4; ++j) {
                const float* pr = src + (size_t)(ci0 + j) * HW_ + wbase;
                if (rowok && wbase >= 0 && wbase + 3 < W_) {
                    float4 f = *(const float4*)pr;
                    vv[j][0] = f.x; vv[j][1] = f.y; vv[j][2] = f.z; vv[j][3] = f.w;
                } else {
                    #pragma unroll
                    for (int i = 0; i < 4; ++i) {
                        const int wg = wbase + i;
                        vv[j][i] = (rowok && wg >= 0 && wg < W_) ? pr[i] : 0.0f;
                    }
                }
            }
            #pragma unroll
            for (int i = 0; i < 4; ++i) {
                const int p = pxg * 4 + i - 3;     // xs pixel index
                if (p >= 0 && p < XS_P) {
                    bf16x4 pk;
                    pk[0] = (__bf16)vv[0][i];
                    pk[1] = (__bf16)vv[1][i];
                    pk[2] = (__bf16)vv[2][i];
                    pk[3] = (__bf16)vv[3][i];
                    const int cp = cc ^ ((p >> 1) & 7);
                    *(bf16x4*)&xs[(r * XS_P + p) * 64 + cp * 8 + chalf] = pk;
                }
            }
        }
    }
    __syncthreads();

    // ---- main MFMA loops: groups g = gs, gs+2, ... ----
    const int hh  = col >> 4;          // output row within group
    const int pxl = col & 15;          // output col within group
    // swizzle term is independent of g: ((g*16 + pxl + dw)>>1)&7 == ((pxl+dw)>>1)&7
    const int swz0 = ((pxl + 0) >> 1) & 7;
    const int swz1 = ((pxl + 1) >> 1) & 7;
    const int swz2 = ((pxl + 2) >> 1) & 7;

    for (int g = gs; g < NG; g += 2) {
        f32x16 acc = {};
        #pragma unroll
        for (int s = 0; s < 36; ++s) {
            const int tap = s >> 2;
            const int dh  = tap / 3;
            const int dw  = tap - dh * 3;
            const int swz = (dw == 0) ? swz0 : ((dw == 1) ? swz1 : swz2);
            const int c   = (s & 3) * 2 + kh;      // 8-ci chunk index
            const int cp  = c ^ swz;
            const int pin = g * 16 + pxl + dw;     // xs pixel for this tap
            const bf16x8* bsrc =
                (const bf16x8*)&xs[((hh + dh) * XS_P + pin) * 64 + cp * 8];
            acc = __builtin_amdgcn_mfma_f32_32x32x16_bf16(afrag[s], *bsrc, acc, 0, 0, 0);
        }
        // D: col = n = (hh, pxl), row = co_local = (r&3) + 8*(r>>2) + 4*kh
        float* op = out + ((size_t)bb * COUT_ + ct * 32 + 4 * kh) * (size_t)HW_
                        + (size_t)(h0 + hh) * W_ + (w0 + g * 16 + pxl);
        #pragma unroll
        for (int r = 0; r < 16; ++r) {
            const int co_r = (r & 3) + 8 * (r >> 2);
            op[(size_t)co_r * HW_] = acc[r] + biasr[r];
        }
    }
}

extern "C" void kernel_launch(void* const* d_in, const int* in_sizes, int n_in,
                              void* d_out, int out_size, void* d_ws, size_t ws_size,
                              hipStream_t stream) {
    const float* x    = (const float*)d_in[0];
    const float* w    = (const float*)d_in[1];
    const float* bias = (const float*)d_in[2];
    float* out = (float*)d_out;
    __bf16* wp = (__bf16*)d_ws;   // 9*64*64*2 = 73728 B

    bc_prep<<<dim3((COUT_ * CIN_ * 9 + 255) / 256), dim3(256), 0, stream>>>(w, wp);
    bc_main<<<dim3(H_ / HT, W_ / WTILE, BATCH), dim3(256), 0, stream>>>(x, wp, bias, out);
}